// Round 16
// baseline (57.631 us; speedup 1.0000x reference)
//
#include <hip/hip_runtime.h>
#include <math.h>

// Retention via chunked linear attention — R15 structure (ushort4 -> bf4 rename).
//   k_y (grid NCH+64): yc[b,c][k] = sum_{chunk} ks[m]*xk[b,m][k]; blocks>=256
//        build wtg = W^T bf16 (global).
//   k_big (1024 thr, 75.7KB LDS, 4 barriers): proj reads wtg from global;
//        kT/vT scattered straight from MFMA accumulators; qkv[2] eliminated.
//   k_gscan (256 thr): 4-wave hierarchical exclusive chunk-prefix of Hc.
//   k_out (grid NCHx2, 512 thr): out = Q'@SE + A@V', column-split, 2 blocks/CU.
// csp identity: sum_{m<64c} K''[m] = (sum_{m<64c} ks[m]*xk[m]) @ W (exact).

constexpr int B = 8, S = 2048, D = 128;
constexpr int C = 64, NC = S / C;
constexpr int BS = B * S;
constexpr int NCH = B * NC;            // 256 chunks
#define GAMMA_F 0.9865f

typedef __attribute__((ext_vector_type(8))) short short8;
typedef __attribute__((ext_vector_type(8))) unsigned short ushort8;
typedef __attribute__((ext_vector_type(4))) unsigned short bf4;
typedef __attribute__((ext_vector_type(4))) float f32x4;

__device__ inline unsigned short f2bf(float f) {
  unsigned u = __builtin_bit_cast(unsigned, f);
  return (unsigned short)((u + 0x7FFF + ((u >> 16) & 1)) >> 16);   // RNE
}
__device__ inline float bf2f(unsigned short h) {
  return __builtin_bit_cast(float, (unsigned)h << 16);
}

// ---------------- K0: yc (blocks 0..255) + wtg build (blocks 256..319) ----------
__global__ __launch_bounds__(128) void k_y(const float* __restrict__ xk,
                                           const float* __restrict__ W,
                                           float* __restrict__ yc,
                                           unsigned short* __restrict__ wtg) {
  int bid = blockIdx.x, tid = threadIdx.x;
  if (bid >= NCH) {   // wtg: 64 blocks x 256 elems
    int e0 = (bid - NCH) * 256 + tid;
#pragma unroll
    for (int h = 0; h < 2; h++) {
      int e = e0 + h * 128;
      int c = e >> 7, k = e & 127;
      wtg[c * 128 + k] = f2bf(W[k * 128 + c]);
    }
    return;
  }
  __shared__ float ksl[64];
  float lgf = logf(GAMMA_F);
  if (tid < 64) {
    int n = (bid * 64 + tid) & (S - 1);
    float rs = (expf(-lgf * (float)(n + 1)) - 1.f) * (GAMMA_F / (1.f - GAMMA_F));
    ksl[tid] = expf(lgf * (float)n) / sqrtf(rs);     // gamma^n / sqrt(rowsum)
  }
  __syncthreads();
  const float* x = xk + (size_t)bid * 64 * 128 + tid;
  float a = 0.f;
#pragma unroll
  for (int j = 0; j < 64; j++) a = fmaf(ksl[j], x[j * 128], a);
  yc[(size_t)bid * 128 + tid] = a;
}

// ---------------- K1: fused proj + mid (1024 threads, 75.7 KB LDS) --------------
__global__ __launch_bounds__(1024, 1) void k_big(
    const float* __restrict__ xq, const float* __restrict__ xk,
    const float* __restrict__ xv, const unsigned short* __restrict__ wtg,
    const float* __restrict__ yc, unsigned short* __restrict__ qb,
    unsigned short* __restrict__ al, unsigned short* __restrict__ vbT,
    unsigned short* __restrict__ Hc) {
  __shared__ unsigned short qkv[2][64][136];   // 34.8 KB  Q', K'' (row-major)
  __shared__ unsigned short kT[128][72];       // 18.4 KB  K''^T (m-fast)
  __shared__ unsigned short vT[128][72];       // 18.4 KB  V^T (raw, scaled in P4)
  __shared__ float cspp[8][128];               //  4 KB
  __shared__ float ysum[128];
  __shared__ float invl[64];
  __shared__ float rsum_l[4][64];

  int bc = blockIdx.x, b = bc >> 5, c = bc & 31;
  int tid = threadIdx.x, w = tid >> 6, lane = tid & 63;
  int l15 = lane & 15, kg = (lane >> 4) * 8;
  float lgf = logf(GAMMA_F);

  // ysum = f32 prefix of yc over prior chunks (runs alongside P1)
  if (tid < 128) {
    float a = 0.f;
    for (int cc = 0; cc < c; cc++) a += yc[(size_t)(b * NC + cc) * 128 + tid];
    ysum[tid] = a;
  }

  // ---- P1: projections. Wave w: rt=w&3 rows, cq=w>>2 col-quarter (2 j-groups).
  // mat0 -> qkv[0]; mat1 -> qkv[1] + kT scatter; mat2 -> vT scatter only.
  {
    int rt = w & 3, cq = w >> 2;
    int arow = rt * 16 + l15;
    int crow = rt * 16 + (lane >> 4) * 4;
    size_t grow = (size_t)(bc * 64 + arow) * 128;
    for (int mat = 0; mat < 3; mat++) {
      const float* X = (mat == 0) ? xq : ((mat == 1) ? xk : xv);
      f32x4 acc[2];
#pragma unroll
      for (int j = 0; j < 2; j++) acc[j] = (f32x4){0.f, 0.f, 0.f, 0.f};
#pragma unroll
      for (int t = 0; t < 4; t++) {
        int k0 = t * 32 + kg;
        const float* ap = X + grow + k0;
        float a8[8];
        *(f32x4*)(a8) = *(const f32x4*)ap;
        *(f32x4*)(a8 + 4) = *(const f32x4*)(ap + 4);
        short8 af;
#pragma unroll
        for (int i = 0; i < 8; i++) af[i] = (short)f2bf(a8[i]);
#pragma unroll
        for (int j = 0; j < 2; j++) {
          short8 bf = *(const short8*)(wtg + (size_t)((cq * 2 + j) * 16 + l15) * 128 + k0);
          acc[j] = __builtin_amdgcn_mfma_f32_16x16x32_bf16(af, bf, acc[j], 0, 0, 0);
        }
      }
      // scales per output row
      float sv[2][4];
#pragma unroll
      for (int rr = 0; rr < 4; rr++) {
        int n = (bc * 64 + crow + rr) & (S - 1);
        float sc;
        if (mat == 0) {
          sc = expf(-lgf * (float)n) * 0.088388347f;          // gamma^-n/sqrt(128)
        } else if (mat == 1) {
          float rs = (expf(-lgf * (float)(n + 1)) - 1.f) * (GAMMA_F / (1.f - GAMMA_F));
          sc = expf(lgf * (float)n) / sqrtf(rs);              // gamma^n/sqrt(rowsum)
        } else {
          sc = 1.f;
        }
#pragma unroll
        for (int j = 0; j < 2; j++) sv[j][rr] = acc[j][rr] * sc;
      }
      if (mat < 2) {   // row-major LDS (A-operands for A-tile, s-dot)
#pragma unroll
        for (int rr = 0; rr < 4; rr++)
#pragma unroll
          for (int j = 0; j < 2; j++)
            qkv[mat][crow + rr][(cq * 2 + j) * 16 + l15] = f2bf(sv[j][rr]);
      }
      if (mat == 1) {  // kT[d][m] scatter: d = col, m = crow..crow+3 (one b64)
#pragma unroll
        for (int j = 0; j < 2; j++) {
          bf4 pk;
#pragma unroll
          for (int rr = 0; rr < 4; rr++) pk[rr] = f2bf(sv[j][rr]);
          *(bf4*)&kT[(cq * 2 + j) * 16 + l15][crow] = pk;
        }
      }
      if (mat == 2) {  // vT[d][m] scatter (raw V)
#pragma unroll
        for (int j = 0; j < 2; j++) {
          bf4 pk;
#pragma unroll
          for (int rr = 0; rr < 4; rr++) pk[rr] = f2bf(sv[j][rr]);
          *(bf4*)&vT[(cq * 2 + j) * 16 + l15][crow] = pk;
        }
      }
    }
  }
  __syncthreads();   // B1: qkv, kT, vT(raw), ysum ready

  // ---- P2: cspp partials | qb write | A-tile -> al + rsum_l ----
  {
    int d = tid & 127, q = tid >> 7;
    const unsigned short* wr = wtg + (size_t)d * 128 + q * 16;
    float part = 0.f;
#pragma unroll
    for (int k = 0; k < 16; k++) part = fmaf(ysum[q * 16 + k], bf2f(wr[k]), part);
    cspp[q][d] = part;
  }
  {  // qb global write (coalesced ushort8)
    int row = tid >> 4, col = (tid & 15) * 8;
    *(ushort8*)(qb + (size_t)(bc * 64 + row) * 128 + col) =
        *(const ushort8*)&qkv[0][row][col];
  }
  {  // A = tril(Q'K''^T): wave (rt2=w&3, mt=w>>2)
    int rt2 = w & 3, mt = w >> 2;
    int arow = rt2 * 16 + l15;
    int crow = rt2 * 16 + (lane >> 4) * 4;
    f32x4 a1 = (f32x4){0.f, 0.f, 0.f, 0.f};
#pragma unroll
    for (int t = 0; t < 4; t++) {
      int k0 = t * 32 + kg;
      short8 af = *(const short8*)&qkv[0][arow][k0];
      short8 bf = *(const short8*)&qkv[1][mt * 16 + l15][k0];
      a1 = __builtin_amdgcn_mfma_f32_16x16x32_bf16(af, bf, a1, 0, 0, 0);
    }
    unsigned short* alg = al + (size_t)bc * 64 * 64;
    float rsp[4];
#pragma unroll
    for (int rr = 0; rr < 4; rr++) {
      int n_l = crow + rr, m_l = mt * 16 + l15;
      float mv = (n_l >= m_l) ? a1[rr] : 0.f;
      alg[n_l * 64 + m_l] = f2bf(mv);
      rsp[rr] = mv;
    }
#pragma unroll
    for (int rr = 0; rr < 4; rr++) {
      float r = rsp[rr];
      r += __shfl_xor(r, 1); r += __shfl_xor(r, 2);
      r += __shfl_xor(r, 4); r += __shfl_xor(r, 8);
      if (l15 == 0) rsum_l[mt][crow + rr] = r;
    }
  }
  __syncthreads();   // B2: cspp, rsum_l ready

  // ---- P3: s = rowsum(A) + Q'.csp (csp summed from cspp inline); invl ----
  {
    int row = tid >> 4, part = tid & 15;
    ushort8 q8 = *(const ushort8*)&qkv[0][row][part * 8];
    float dot = 0.f;
#pragma unroll
    for (int ii = 0; ii < 8; ii++) {
      int kk = part * 8 + ii;
      float csum = cspp[0][kk] + cspp[1][kk] + cspp[2][kk] + cspp[3][kk] +
                   cspp[4][kk] + cspp[5][kk] + cspp[6][kk] + cspp[7][kk];
      dot = fmaf(bf2f(q8[ii]), csum, dot);
    }
    dot += __shfl_xor(dot, 1); dot += __shfl_xor(dot, 2);
    dot += __shfl_xor(dot, 4); dot += __shfl_xor(dot, 8);
    if (part == 0) {
      float s = rsum_l[0][row] + rsum_l[1][row] + rsum_l[2][row] + rsum_l[3][row] + dot;
      invl[row] = 1.f / fmaxf(fabsf(s), 1.f);
    }
  }
  __syncthreads();   // B3: invl ready

  // ---- P4: vT *= invl[m] (8 elems/thread: 1024x8 = 128x64) ----
  {
    int d = tid >> 3, ms = (tid & 7) * 8;
    ushort8 v8 = *(const ushort8*)&vT[d][ms];
    ushort8 o;
#pragma unroll
    for (int ii = 0; ii < 8; ii++) o[ii] = f2bf(bf2f(v8[ii]) * invl[ms + ii]);
    *(ushort8*)&vT[d][ms] = o;
  }
  __syncthreads();   // B4: vT = V'^T ready

  // ---- P5: Hc = (K''^T V')^T via MFMA ; vbT global write ----
  {
    int d2t = w >> 1, jh = w & 1;
    f32x4 hacc[4];
#pragma unroll
    for (int j = 0; j < 4; j++) hacc[j] = (f32x4){0.f, 0.f, 0.f, 0.f};
#pragma unroll
    for (int t = 0; t < 2; t++) {
      int k0 = t * 32 + kg;
      short8 a2 = *(const short8*)&vT[d2t * 16 + l15][k0];
#pragma unroll
      for (int j = 0; j < 4; j++) {
        short8 bf = *(const short8*)&kT[(jh * 4 + j) * 16 + l15][k0];
        hacc[j] = __builtin_amdgcn_mfma_f32_16x16x32_bf16(a2, bf, hacc[j], 0, 0, 0);
      }
    }
    unsigned short* g = Hc + (size_t)bc * D * D;
#pragma unroll
    for (int j = 0; j < 4; j++)
#pragma unroll
      for (int rr = 0; rr < 4; rr++)
        g[(size_t)(d2t * 16 + (lane >> 4) * 4 + rr) * D + (jh * 4 + j) * 16 + l15] =
            f2bf(hacc[j][rr]);
  }
  {
    int d = tid >> 3, pp = (tid & 7) * 8;
    *(ushort8*)(vbT + (size_t)bc * D * C + (size_t)d * C + pp) =
        *(const ushort8*)&vT[d][pp];
  }
}

// ---------------- K2: hierarchical exclusive chunk-prefix of Hc (4 waves) -------
__global__ __launch_bounds__(256) void k_gscan(const unsigned short* __restrict__ Hc,
                                               unsigned short* __restrict__ HS) {
  __shared__ float ttot[4][64][8];
  int b = blockIdx.x, gy = blockIdx.y;
  int tid = threadIdx.x, g = tid >> 6, slot = tid & 63;
  int d2 = gy * 4 + (slot >> 4), d1 = (slot & 15) * 8;
  size_t off = ((size_t)(b * NC) * D + d2) * D + d1;
  ushort8 v[8];
  float tot[8];
#pragma unroll
  for (int j = 0; j < 8; j++) tot[j] = 0.f;
#pragma unroll
  for (int i = 0; i < 8; i++) {
    v[i] = *(const ushort8*)(Hc + off + (size_t)(g * 8 + i) * D * D);
#pragma unroll
    for (int j = 0; j < 8; j++) tot[j] += bf2f(v[i][j]);
  }
#pragma unroll
  for (int j = 0; j < 8; j++) ttot[g][slot][j] = tot[j];
  __syncthreads();
  float run[8];
#pragma unroll
  for (int j = 0; j < 8; j++) run[j] = 0.f;
  for (int gg = 0; gg < 4; gg++)
    if (gg < g)
#pragma unroll
      for (int j = 0; j < 8; j++) run[j] += ttot[gg][slot][j];
#pragma unroll
  for (int i = 0; i < 8; i++) {
    ushort8 o;
#pragma unroll
    for (int j = 0; j < 8; j++) {
      o[j] = f2bf(run[j]);
      run[j] += bf2f(v[i][j]);
    }
    *(ushort8*)(HS + off + (size_t)(g * 8 + i) * D * D) = o;
  }
}

// ---------------- K3: out = Q'@SE + A@V' (grid NCHx2, 512 thr, no LDS) ----------
__global__ __launch_bounds__(512) void k_out(
    const unsigned short* __restrict__ qb, const unsigned short* __restrict__ al,
    const unsigned short* __restrict__ vbT, const unsigned short* __restrict__ HS,
    float* __restrict__ out) {
  int bc = blockIdx.x, ch2 = blockIdx.y;
  int tid = threadIdx.x, w = tid >> 6, lane = tid & 63;
  int l15 = lane & 15;
  size_t base = (size_t)bc * C * D;
  int kg = (lane >> 4) * 8;
  int rt = w >> 1, chw = w & 1;
  int arow = rt * 16 + l15;
  int crow = rt * 16 + (lane >> 4) * 4;

  f32x4 acc[2];
#pragma unroll
  for (int j = 0; j < 2; j++) acc[j] = (f32x4){0.f, 0.f, 0.f, 0.f};
  const unsigned short* hrow = HS + (size_t)bc * D * D;
#pragma unroll
  for (int t = 0; t < 4; t++) {
    int k0 = t * 32 + kg;
    short8 af = *(const short8*)(qb + base + (size_t)arow * D + k0);
#pragma unroll
    for (int jj = 0; jj < 2; jj++) {
      int j = ch2 * 4 + chw * 2 + jj;
      short8 bf = *(const short8*)(hrow + (size_t)(j * 16 + l15) * D + k0);
      acc[jj] = __builtin_amdgcn_mfma_f32_16x16x32_bf16(af, bf, acc[jj], 0, 0, 0);
    }
  }
  const unsigned short* alg = al + (size_t)bc * 64 * 64;
  const unsigned short* vt = vbT + (size_t)bc * D * C;
#pragma unroll
  for (int t = 0; t < 2; t++) {
    int k0 = t * 32 + kg;
    short8 af = *(const short8*)(alg + (size_t)arow * 64 + k0);
#pragma unroll
    for (int jj = 0; jj < 2; jj++) {
      int j = ch2 * 4 + chw * 2 + jj;
      short8 bf = *(const short8*)(vt + (size_t)(j * 16 + l15) * C + k0);
      acc[jj] = __builtin_amdgcn_mfma_f32_16x16x32_bf16(af, bf, acc[jj], 0, 0, 0);
    }
  }
#pragma unroll
  for (int jj = 0; jj < 2; jj++)
#pragma unroll
    for (int rr = 0; rr < 4; rr++)
      out[base + (size_t)(crow + rr) * D + (ch2 * 4 + chw * 2 + jj) * 16 + l15] =
          acc[jj][rr];
}

extern "C" void kernel_launch(void* const* d_in, const int* in_sizes, int n_in,
                              void* d_out, int out_size, void* d_ws, size_t ws_size,
                              hipStream_t stream) {
  const float* xq = (const float*)d_in[0];
  const float* xk = (const float*)d_in[1];
  const float* xv = (const float*)d_in[2];
  const float* W  = (const float*)d_in[3];
  float* out = (float*)d_out;

  char* p = (char*)d_ws;
  float* yc = (float*)p;                     p += (size_t)NCH * D * 4;
  unsigned short* wtg = (unsigned short*)p;  p += (size_t)D * D * 2;
  unsigned short* qb  = (unsigned short*)p;  p += (size_t)BS * D * 2;
  unsigned short* al  = (unsigned short*)p;  p += (size_t)NCH * C * C * 2;
  unsigned short* vbT = (unsigned short*)p;  p += (size_t)NCH * D * C * 2;
  unsigned short* Hc  = (unsigned short*)p;  p += (size_t)NCH * D * D * 2;
  unsigned short* HS  = (unsigned short*)p;  p += (size_t)NCH * D * D * 2;

  hipLaunchKernelGGL(k_y, dim3(NCH + 64), dim3(128), 0, stream, xk, W, yc, wtg);
  hipLaunchKernelGGL(k_big, dim3(NCH), dim3(1024), 0, stream,
                     xq, xk, xv, wtg, yc, qb, al, vbT, Hc);
  hipLaunchKernelGGL(k_gscan, dim3(B, 32), dim3(256), 0, stream, Hc, HS);
  hipLaunchKernelGGL(k_out, dim3(NCH, 2), dim3(512), 0, stream, qb, al, vbT, HS, out);
}

// Round 18
// 52.421 us; speedup vs baseline: 1.0994x; 1.0994x over previous
//
#include <hip/hip_runtime.h>
#include <math.h>

// Retention via chunked linear attention — R17 = R11 base (best, 51.6us)
// + hierarchical gscan (256 thr) + column-split k_out (grid NCHx2).
//   k_y:    yc[b,c][k] = sum_{m in chunk c} ks[m]*xk[b,m][k]
//   k_big:  per chunk (512 thr): W^T LDS; Q',K'',V proj in LDS; csp=(prefix yc)@W;
//           A = tril(Q'K''^T) -> al; s = rowsum(A)+Q'.csp; V'=V/max(|s|,1);
//           kT/vT packs; Hc = (K''^T V')^T -> global; qb, vbT -> global
//   k_gscan: HS = exclusive chunk prefix of Hc (4-wave hierarchical)
//   k_out:  out = Q'@SE + A@V'  (512 thr, no LDS, 2 blocks/CU)
// csp identity: sum_{m<64c} K''[m] = (sum_{m<64c} ks[m]*xk[m]) @ W (exact).

constexpr int B = 8, S = 2048, D = 128;
constexpr int C = 64, NC = S / C;
constexpr int BS = B * S;
constexpr int NCH = B * NC;            // 256 chunks
#define GAMMA_F 0.9865f

typedef __attribute__((ext_vector_type(8))) short short8;
typedef __attribute__((ext_vector_type(8))) unsigned short ushort8;
typedef __attribute__((ext_vector_type(4))) float f32x4;

__device__ inline unsigned short f2bf(float f) {
  unsigned u = __builtin_bit_cast(unsigned, f);
  return (unsigned short)((u + 0x7FFF + ((u >> 16) & 1)) >> 16);   // RNE
}
__device__ inline float bf2f(unsigned short h) {
  return __builtin_bit_cast(float, (unsigned)h << 16);
}

// ---------------- K0: per-chunk ks-weighted xk column sums ----------------
__global__ __launch_bounds__(128) void k_y(const float* __restrict__ xk,
                                           float* __restrict__ yc) {
  __shared__ float ksl[64];
  int bc = blockIdx.x, tid = threadIdx.x;
  float lgf = logf(GAMMA_F);
  if (tid < 64) {
    int n = (bc * 64 + tid) & (S - 1);
    float rs = (expf(-lgf * (float)(n + 1)) - 1.f) * (GAMMA_F / (1.f - GAMMA_F));
    ksl[tid] = expf(lgf * (float)n) / sqrtf(rs);     // gamma^n / sqrt(rowsum)
  }
  __syncthreads();
  const float* x = xk + (size_t)bc * 64 * 128 + tid;
  float a = 0.f;
#pragma unroll
  for (int j = 0; j < 64; j++) a = fmaf(ksl[j], x[j * 128], a);
  yc[(size_t)bc * 128 + tid] = a;
}

// ---------------- K1: fused proj + mid (512 threads, ~92 KB LDS) ----------------
__global__ __launch_bounds__(512) void k_big(
    const float* __restrict__ xq, const float* __restrict__ xk,
    const float* __restrict__ xv, const float* __restrict__ W,
    const float* __restrict__ yc, unsigned short* __restrict__ qb,
    unsigned short* __restrict__ al, unsigned short* __restrict__ vbT,
    unsigned short* __restrict__ Hc) {
  __shared__ unsigned short qkv[3][64][136];       // 52.2 KB  Q',K'',V(->V' via vT)
  __shared__ alignas(16) char ovl[36864];          // 36.9 KB  wt then kT+vT
  __shared__ float csp[128];
  __shared__ float ysum[128];
  __shared__ float cspp[4][128];
  __shared__ float invl[64];
  __shared__ float rsum_l[2][64];
  auto wt = (unsigned short(*)[136])ovl;           // P0..P1 only
  auto kT = (unsigned short(*)[72])ovl;            // P2 onward
  auto vT = (unsigned short(*)[72])(ovl + 18432);  // P2 onward

  int bc = blockIdx.x, b = bc >> 5, c = bc & 31;
  int tid = threadIdx.x, w = tid >> 6, lane = tid & 63;
  int l15 = lane & 15, kg = (lane >> 4) * 8;
  float lgf = logf(GAMMA_F);

  // ---- P0: wt = W^T (bf16, LDS); ysum = prefix of yc ----
  for (int idx = tid; idx < 128 * 128; idx += 512) {
    int cc = idx >> 7, k = idx & 127;
    wt[cc][k] = f2bf(W[k * 128 + cc]);
  }
  if (tid < 128) {
    float a = 0.f;
    for (int cc = 0; cc < c; cc++) a += yc[(size_t)(b * NC + cc) * 128 + tid];
    ysum[tid] = a;
  }
  __syncthreads();

  // ---- P1: projections into LDS. Wave w: rt rows, chh col-half ----
  int rt = w & 3, chh = w >> 2;
  {
    int arow = rt * 16 + l15;
    size_t grow = (size_t)(bc * 64 + arow) * 128;
    for (int mat = 0; mat < 3; mat++) {
      const float* X = (mat == 0) ? xq : ((mat == 1) ? xk : xv);
      f32x4 acc[4];
#pragma unroll
      for (int j = 0; j < 4; j++) acc[j] = (f32x4){0.f, 0.f, 0.f, 0.f};
#pragma unroll
      for (int t = 0; t < 4; t++) {
        int k0 = t * 32 + kg;
        const float* ap = X + grow + k0;
        float a8[8];
        *(f32x4*)(a8) = *(const f32x4*)ap;
        *(f32x4*)(a8 + 4) = *(const f32x4*)(ap + 4);
        short8 af;
#pragma unroll
        for (int i = 0; i < 8; i++) af[i] = (short)f2bf(a8[i]);
#pragma unroll
        for (int j = 0; j < 4; j++) {
          short8 bf = *(const short8*)&wt[(chh * 4 + j) * 16 + l15][k0];
          acc[j] = __builtin_amdgcn_mfma_f32_16x16x32_bf16(af, bf, acc[j], 0, 0, 0);
        }
      }
      int crow = rt * 16 + (lane >> 4) * 4;
#pragma unroll
      for (int rr = 0; rr < 4; rr++) {
        int row = crow + rr;
        int n = (bc * 64 + row) & (S - 1);
        float sc;
        if (mat == 0) {
          sc = expf(-lgf * (float)n) * 0.088388347f;          // gamma^-n/sqrt(128)
        } else if (mat == 1) {
          float rs = (expf(-lgf * (float)(n + 1)) - 1.f) * (GAMMA_F / (1.f - GAMMA_F));
          sc = expf(lgf * (float)n) / sqrtf(rs);              // gamma^n/sqrt(rowsum)
        } else {
          sc = 1.f;
        }
#pragma unroll
        for (int j = 0; j < 4; j++)
          qkv[mat][row][(chh * 4 + j) * 16 + l15] = f2bf(acc[j][rr] * sc);
      }
    }
  }
  // ---- P1b: csp partials = ysum @ wt (per-quarter) ----
  {
    int d = tid & 127, q = tid >> 7;
    float part = 0.f;
#pragma unroll
    for (int k = 0; k < 32; k++) part = fmaf(ysum[32 * q + k], bf2f(wt[d][32 * q + k]), part);
    cspp[q][d] = part;
  }
  __syncthreads();   // qkv, cspp ready; wt dead -> ovl becomes kT/vT

  // ---- P2: qb write | A-tile -> al,rsum | kT pack | vT raw pack | csp finalize ----
  if (tid < 128) csp[tid] = cspp[0][tid] + cspp[1][tid] + cspp[2][tid] + cspp[3][tid];
  {  // qb global write
    int row = tid >> 3, col = (tid & 7) * 16;
    unsigned short* dst = qb + (size_t)(bc * 64 + row) * 128 + col;
    *(ushort8*)dst = *(const ushort8*)&qkv[0][row][col];
    *(ushort8*)(dst + 8) = *(const ushort8*)&qkv[0][row][col + 8];
  }
  {  // A = tril(Q'K''^T): wave w: rt2=w&3 rows, mh=w>>2 col pair
    int rt2 = w & 3, mh = w >> 2;
    int arow = rt2 * 16 + l15;
    int crow = rt2 * 16 + (lane >> 4) * 4;
    f32x4 a1[2];
#pragma unroll
    for (int mi = 0; mi < 2; mi++) a1[mi] = (f32x4){0.f, 0.f, 0.f, 0.f};
#pragma unroll
    for (int t = 0; t < 4; t++) {
      int k0 = t * 32 + kg;
      short8 af = *(const short8*)&qkv[0][arow][k0];
#pragma unroll
      for (int mi = 0; mi < 2; mi++) {
        short8 bf = *(const short8*)&qkv[1][(mh * 2 + mi) * 16 + l15][k0];
        a1[mi] = __builtin_amdgcn_mfma_f32_16x16x32_bf16(af, bf, a1[mi], 0, 0, 0);
      }
    }
    unsigned short* alg = al + (size_t)bc * 64 * 64;
    float rsp[4] = {0.f, 0.f, 0.f, 0.f};
#pragma unroll
    for (int mi = 0; mi < 2; mi++)
#pragma unroll
      for (int rr = 0; rr < 4; rr++) {
        int n_l = crow + rr, m_l = (mh * 2 + mi) * 16 + l15;
        float mv = (n_l >= m_l) ? a1[mi][rr] : 0.f;
        alg[n_l * 64 + m_l] = f2bf(mv);
        rsp[rr] += mv;
      }
#pragma unroll
    for (int rr = 0; rr < 4; rr++) {
      float r = rsp[rr];
      r += __shfl_xor(r, 1); r += __shfl_xor(r, 2);
      r += __shfl_xor(r, 4); r += __shfl_xor(r, 8);
      if (l15 == 0) rsum_l[mh][crow + rr] = r;
    }
  }
  {  // kT pack (K''^T, m-fast)
    int d = tid & 127, mh2 = tid >> 7;
#pragma unroll
    for (int mg = 0; mg < 2; mg++) {
      ushort8 pk;
#pragma unroll
      for (int i = 0; i < 8; i++) pk[i] = qkv[1][mh2 * 16 + mg * 8 + i][d];
      *(ushort8*)&kT[d][mh2 * 16 + mg * 8] = pk;
    }
  }
  {  // vT raw pack (V^T, unscaled)
    int d = tid & 127, mh2 = tid >> 7;
#pragma unroll
    for (int mg = 0; mg < 2; mg++) {
      ushort8 pk;
#pragma unroll
      for (int i = 0; i < 8; i++) pk[i] = qkv[2][mh2 * 16 + mg * 8 + i][d];
      *(ushort8*)&vT[d][mh2 * 16 + mg * 8] = pk;
    }
  }
  __syncthreads();   // csp, rsum_l, kT, vT(raw) ready

  // ---- P3: s = rowsum(A) + Q'.csp ; invl ----
  {
    int row = tid >> 3, part = tid & 7;
    ushort8 q8a = *(const ushort8*)&qkv[0][row][part * 16];
    ushort8 q8b = *(const ushort8*)&qkv[0][row][part * 16 + 8];
    float dot = 0.f;
#pragma unroll
    for (int ii = 0; ii < 8; ii++) {
      dot = fmaf(bf2f(q8a[ii]), csp[part * 16 + ii], dot);
      dot = fmaf(bf2f(q8b[ii]), csp[part * 16 + 8 + ii], dot);
    }
    dot += __shfl_xor(dot, 1); dot += __shfl_xor(dot, 2); dot += __shfl_xor(dot, 4);
    if (part == 0) {
      float s = rsum_l[0][row] + rsum_l[1][row] + dot;
      invl[row] = 1.f / fmaxf(fabsf(s), 1.f);
    }
  }
  __syncthreads();   // invl ready

  // ---- P4: scale vT in place by invl[m] ----
  {
    int d = tid >> 2, ms = (tid & 3) * 16;
#pragma unroll
    for (int g = 0; g < 2; g++) {
      ushort8 v8 = *(const ushort8*)&vT[d][ms + g * 8];
      ushort8 o;
#pragma unroll
      for (int ii = 0; ii < 8; ii++) o[ii] = f2bf(bf2f(v8[ii]) * invl[ms + g * 8 + ii]);
      *(ushort8*)&vT[d][ms + g * 8] = o;
    }
  }
  __syncthreads();   // vT = V'^T ready

  // ---- P5: Hc = (K''^T V')^T via MFMA ; vbT global write ----
  {
    f32x4 hacc[8];
#pragma unroll
    for (int j = 0; j < 8; j++) hacc[j] = (f32x4){0.f, 0.f, 0.f, 0.f};
#pragma unroll
    for (int t = 0; t < 2; t++) {
      int k0 = t * 32 + kg;
      short8 a2 = *(const short8*)&vT[w * 16 + l15][k0];
#pragma unroll
      for (int j = 0; j < 8; j++) {
        short8 bf = *(const short8*)&kT[j * 16 + l15][k0];
        hacc[j] = __builtin_amdgcn_mfma_f32_16x16x32_bf16(a2, bf, hacc[j], 0, 0, 0);
      }
    }
    unsigned short* g = Hc + (size_t)bc * D * D;
#pragma unroll
    for (int j = 0; j < 8; j++)
#pragma unroll
      for (int rr = 0; rr < 4; rr++)
        g[(size_t)(w * 16 + (lane >> 4) * 4 + rr) * D + j * 16 + l15] =
            f2bf(hacc[j][rr]);
  }
  {
    int d = tid >> 2, pp = (tid & 3) * 16;
    unsigned short* dst = vbT + (size_t)bc * D * C + (size_t)d * C + pp;
    *(ushort8*)(dst) = *(const ushort8*)&vT[d][pp];
    *(ushort8*)(dst + 8) = *(const ushort8*)&vT[d][pp + 8];
  }
}

// ---------------- K2: hierarchical exclusive chunk-prefix of Hc (4 waves) -------
__global__ __launch_bounds__(256) void k_gscan(const unsigned short* __restrict__ Hc,
                                               unsigned short* __restrict__ HS) {
  __shared__ float ttot[4][64][8];
  int b = blockIdx.x, gy = blockIdx.y;
  int tid = threadIdx.x, g = tid >> 6, slot = tid & 63;
  int d2 = gy * 4 + (slot >> 4), d1 = (slot & 15) * 8;
  size_t off = ((size_t)(b * NC) * D + d2) * D + d1;
  ushort8 v[8];
  float tot[8];
#pragma unroll
  for (int j = 0; j < 8; j++) tot[j] = 0.f;
#pragma unroll
  for (int i = 0; i < 8; i++) {
    v[i] = *(const ushort8*)(Hc + off + (size_t)(g * 8 + i) * D * D);
#pragma unroll
    for (int j = 0; j < 8; j++) tot[j] += bf2f(v[i][j]);
  }
#pragma unroll
  for (int j = 0; j < 8; j++) ttot[g][slot][j] = tot[j];
  __syncthreads();
  float run[8];
#pragma unroll
  for (int j = 0; j < 8; j++) run[j] = 0.f;
  for (int gg = 0; gg < 4; gg++)
    if (gg < g)
#pragma unroll
      for (int j = 0; j < 8; j++) run[j] += ttot[gg][slot][j];
#pragma unroll
  for (int i = 0; i < 8; i++) {
    ushort8 o;
#pragma unroll
    for (int j = 0; j < 8; j++) {
      o[j] = f2bf(run[j]);
      run[j] += bf2f(v[i][j]);
    }
    *(ushort8*)(HS + off + (size_t)(g * 8 + i) * D * D) = o;
  }
}

// ---------------- K3: out = Q'@SE + A@V' (grid NCHx2, 512 thr, no LDS) ----------
__global__ __launch_bounds__(512) void k_out(
    const unsigned short* __restrict__ qb, const unsigned short* __restrict__ al,
    const unsigned short* __restrict__ vbT, const unsigned short* __restrict__ HS,
    float* __restrict__ out) {
  int bc = blockIdx.x, ch2 = blockIdx.y;
  int tid = threadIdx.x, w = tid >> 6, lane = tid & 63;
  int l15 = lane & 15;
  size_t base = (size_t)bc * C * D;
  int kg = (lane >> 4) * 8;
  int rt = w >> 1, chw = w & 1;
  int arow = rt * 16 + l15;
  int crow = rt * 16 + (lane >> 4) * 4;

  f32x4 acc[2];
#pragma unroll
  for (int j = 0; j < 2; j++) acc[j] = (f32x4){0.f, 0.f, 0.f, 0.f};
  const unsigned short* hrow = HS + (size_t)bc * D * D;
#pragma unroll
  for (int t = 0; t < 4; t++) {
    int k0 = t * 32 + kg;
    short8 af = *(const short8*)(qb + base + (size_t)arow * D + k0);
#pragma unroll
    for (int jj = 0; jj < 2; jj++) {
      int j = ch2 * 4 + chw * 2 + jj;
      short8 bf = *(const short8*)(hrow + (size_t)(j * 16 + l15) * D + k0);
      acc[jj] = __builtin_amdgcn_mfma_f32_16x16x32_bf16(af, bf, acc[jj], 0, 0, 0);
    }
  }
  const unsigned short* alg = al + (size_t)bc * 64 * 64;
  const unsigned short* vt = vbT + (size_t)bc * D * C;
#pragma unroll
  for (int t = 0; t < 2; t++) {
    int k0 = t * 32 + kg;
    short8 af = *(const short8*)(alg + (size_t)arow * 64 + k0);
#pragma unroll
    for (int jj = 0; jj < 2; jj++) {
      int j = ch2 * 4 + chw * 2 + jj;
      short8 bf = *(const short8*)(vt + (size_t)(j * 16 + l15) * C + k0);
      acc[jj] = __builtin_amdgcn_mfma_f32_16x16x32_bf16(af, bf, acc[jj], 0, 0, 0);
    }
  }
#pragma unroll
  for (int jj = 0; jj < 2; jj++)
#pragma unroll
    for (int rr = 0; rr < 4; rr++)
      out[base + (size_t)(crow + rr) * D + (ch2 * 4 + chw * 2 + jj) * 16 + l15] =
          acc[jj][rr];
}

extern "C" void kernel_launch(void* const* d_in, const int* in_sizes, int n_in,
                              void* d_out, int out_size, void* d_ws, size_t ws_size,
                              hipStream_t stream) {
  const float* xq = (const float*)d_in[0];
  const float* xk = (const float*)d_in[1];
  const float* xv = (const float*)d_in[2];
  const float* W  = (const float*)d_in[3];
  float* out = (float*)d_out;

  char* p = (char*)d_ws;
  float* yc = (float*)p;                     p += (size_t)NCH * D * 4;
  unsigned short* qb  = (unsigned short*)p;  p += (size_t)BS * D * 2;
  unsigned short* al  = (unsigned short*)p;  p += (size_t)NCH * C * C * 2;
  unsigned short* vbT = (unsigned short*)p;  p += (size_t)NCH * D * C * 2;
  unsigned short* Hc  = (unsigned short*)p;  p += (size_t)NCH * D * D * 2;
  unsigned short* HS  = (unsigned short*)p;  p += (size_t)NCH * D * D * 2;

  hipLaunchKernelGGL(k_y, dim3(NCH), dim3(128), 0, stream, xk, yc);
  hipLaunchKernelGGL(k_big, dim3(NCH), dim3(512), 0, stream,
                     xq, xk, xv, W, yc, qb, al, vbT, Hc);
  hipLaunchKernelGGL(k_gscan, dim3(B, 32), dim3(256), 0, stream, Hc, HS);
  hipLaunchKernelGGL(k_out, dim3(NCH, 2), dim3(512), 0, stream, qb, al, vbT, HS, out);
}

// Round 19
// 52.000 us; speedup vs baseline: 1.1083x; 1.0081x over previous
//
#include <hip/hip_runtime.h>
#include <math.h>

// Retention via chunked linear attention — FINAL: exact R11 configuration
// (session best, 51.6us). 4 dispatches; ~17us body + ~35us dispatch-boundary
// floor (measured via R10 probes + R8 grid.sync calibration ~25us/sync rules
// out all fusion paths; R13/R14/R15/R16 k_big redesigns all regressed).
//   k_y:    yc[b,c][k] = sum_{m in chunk c} ks[m]*xk[b,m][k]
//   k_big:  per chunk (512 thr): W^T LDS; Q',K'',V proj in LDS; csp=(prefix yc)@W;
//           A = tril(Q'K''^T) -> al; s = rowsum(A)+Q'.csp; V'=V/max(|s|,1);
//           kT/vT packs; Hc = (K''^T V')^T -> global; qb, vbT -> global
//   k_gscan: HS = exclusive chunk prefix of Hc (register-staged, 64 thr)
//   k_out:  out = Q'@SE + A@V'  (512 thr, no LDS)
// csp identity: sum_{m<64c} K''[m] = (sum_{m<64c} ks[m]*xk[m]) @ W (exact).

constexpr int B = 8, S = 2048, D = 128;
constexpr int C = 64, NC = S / C;
constexpr int BS = B * S;
constexpr int NCH = B * NC;            // 256 chunks
#define GAMMA_F 0.9865f

typedef __attribute__((ext_vector_type(8))) short short8;
typedef __attribute__((ext_vector_type(8))) unsigned short ushort8;
typedef __attribute__((ext_vector_type(4))) float f32x4;

__device__ inline unsigned short f2bf(float f) {
  unsigned u = __builtin_bit_cast(unsigned, f);
  return (unsigned short)((u + 0x7FFF + ((u >> 16) & 1)) >> 16);   // RNE
}
__device__ inline float bf2f(unsigned short h) {
  return __builtin_bit_cast(float, (unsigned)h << 16);
}

// ---------------- K0: per-chunk ks-weighted xk column sums ----------------
__global__ __launch_bounds__(128) void k_y(const float* __restrict__ xk,
                                           float* __restrict__ yc) {
  __shared__ float ksl[64];
  int bc = blockIdx.x, tid = threadIdx.x;
  float lgf = logf(GAMMA_F);
  if (tid < 64) {
    int n = (bc * 64 + tid) & (S - 1);
    float rs = (expf(-lgf * (float)(n + 1)) - 1.f) * (GAMMA_F / (1.f - GAMMA_F));
    ksl[tid] = expf(lgf * (float)n) / sqrtf(rs);     // gamma^n / sqrt(rowsum)
  }
  __syncthreads();
  const float* x = xk + (size_t)bc * 64 * 128 + tid;
  float a = 0.f;
#pragma unroll
  for (int j = 0; j < 64; j++) a = fmaf(ksl[j], x[j * 128], a);
  yc[(size_t)bc * 128 + tid] = a;
}

// ---------------- K1: fused proj + mid (512 threads, ~92 KB LDS) ----------------
__global__ __launch_bounds__(512) void k_big(
    const float* __restrict__ xq, const float* __restrict__ xk,
    const float* __restrict__ xv, const float* __restrict__ W,
    const float* __restrict__ yc, unsigned short* __restrict__ qb,
    unsigned short* __restrict__ al, unsigned short* __restrict__ vbT,
    unsigned short* __restrict__ Hc) {
  __shared__ unsigned short qkv[3][64][136];       // 52.2 KB  Q',K'',V(->V' via vT)
  __shared__ alignas(16) char ovl[36864];          // 36.9 KB  wt then kT+vT
  __shared__ float csp[128];
  __shared__ float ysum[128];
  __shared__ float cspp[4][128];
  __shared__ float invl[64];
  __shared__ float rsum_l[2][64];
  auto wt = (unsigned short(*)[136])ovl;           // P0..P1 only
  auto kT = (unsigned short(*)[72])ovl;            // P2 onward
  auto vT = (unsigned short(*)[72])(ovl + 18432);  // P2 onward

  int bc = blockIdx.x, b = bc >> 5, c = bc & 31;
  int tid = threadIdx.x, w = tid >> 6, lane = tid & 63;
  int l15 = lane & 15, kg = (lane >> 4) * 8;
  float lgf = logf(GAMMA_F);

  // ---- P0: wt = W^T (bf16, LDS); ysum = prefix of yc ----
  for (int idx = tid; idx < 128 * 128; idx += 512) {
    int cc = idx >> 7, k = idx & 127;
    wt[cc][k] = f2bf(W[k * 128 + cc]);
  }
  if (tid < 128) {
    float a = 0.f;
    for (int cc = 0; cc < c; cc++) a += yc[(size_t)(b * NC + cc) * 128 + tid];
    ysum[tid] = a;
  }
  __syncthreads();

  // ---- P1: projections into LDS. Wave w: rt rows, chh col-half ----
  int rt = w & 3, chh = w >> 2;
  {
    int arow = rt * 16 + l15;
    size_t grow = (size_t)(bc * 64 + arow) * 128;
    for (int mat = 0; mat < 3; mat++) {
      const float* X = (mat == 0) ? xq : ((mat == 1) ? xk : xv);
      f32x4 acc[4];
#pragma unroll
      for (int j = 0; j < 4; j++) acc[j] = (f32x4){0.f, 0.f, 0.f, 0.f};
#pragma unroll
      for (int t = 0; t < 4; t++) {
        int k0 = t * 32 + kg;
        const float* ap = X + grow + k0;
        float a8[8];
        *(f32x4*)(a8) = *(const f32x4*)ap;
        *(f32x4*)(a8 + 4) = *(const f32x4*)(ap + 4);
        short8 af;
#pragma unroll
        for (int i = 0; i < 8; i++) af[i] = (short)f2bf(a8[i]);
#pragma unroll
        for (int j = 0; j < 4; j++) {
          short8 bf = *(const short8*)&wt[(chh * 4 + j) * 16 + l15][k0];
          acc[j] = __builtin_amdgcn_mfma_f32_16x16x32_bf16(af, bf, acc[j], 0, 0, 0);
        }
      }
      int crow = rt * 16 + (lane >> 4) * 4;
#pragma unroll
      for (int rr = 0; rr < 4; rr++) {
        int row = crow + rr;
        int n = (bc * 64 + row) & (S - 1);
        float sc;
        if (mat == 0) {
          sc = expf(-lgf * (float)n) * 0.088388347f;          // gamma^-n/sqrt(128)
        } else if (mat == 1) {
          float rs = (expf(-lgf * (float)(n + 1)) - 1.f) * (GAMMA_F / (1.f - GAMMA_F));
          sc = expf(lgf * (float)n) / sqrtf(rs);              // gamma^n/sqrt(rowsum)
        } else {
          sc = 1.f;
        }
#pragma unroll
        for (int j = 0; j < 4; j++)
          qkv[mat][row][(chh * 4 + j) * 16 + l15] = f2bf(acc[j][rr] * sc);
      }
    }
  }
  // ---- P1b: csp partials = ysum @ wt (per-quarter) ----
  {
    int d = tid & 127, q = tid >> 7;
    float part = 0.f;
#pragma unroll
    for (int k = 0; k < 32; k++) part = fmaf(ysum[32 * q + k], bf2f(wt[d][32 * q + k]), part);
    cspp[q][d] = part;
  }
  __syncthreads();   // qkv, cspp ready; wt dead -> ovl becomes kT/vT

  // ---- P2: qb write | A-tile -> al,rsum | kT pack | vT raw pack | csp finalize ----
  if (tid < 128) csp[tid] = cspp[0][tid] + cspp[1][tid] + cspp[2][tid] + cspp[3][tid];
  {  // qb global write
    int row = tid >> 3, col = (tid & 7) * 16;
    unsigned short* dst = qb + (size_t)(bc * 64 + row) * 128 + col;
    *(ushort8*)dst = *(const ushort8*)&qkv[0][row][col];
    *(ushort8*)(dst + 8) = *(const ushort8*)&qkv[0][row][col + 8];
  }
  {  // A = tril(Q'K''^T): wave w: rt2=w&3 rows, mh=w>>2 col pair
    int rt2 = w & 3, mh = w >> 2;
    int arow = rt2 * 16 + l15;
    int crow = rt2 * 16 + (lane >> 4) * 4;
    f32x4 a1[2];
#pragma unroll
    for (int mi = 0; mi < 2; mi++) a1[mi] = (f32x4){0.f, 0.f, 0.f, 0.f};
#pragma unroll
    for (int t = 0; t < 4; t++) {
      int k0 = t * 32 + kg;
      short8 af = *(const short8*)&qkv[0][arow][k0];
#pragma unroll
      for (int mi = 0; mi < 2; mi++) {
        short8 bf = *(const short8*)&qkv[1][(mh * 2 + mi) * 16 + l15][k0];
        a1[mi] = __builtin_amdgcn_mfma_f32_16x16x32_bf16(af, bf, a1[mi], 0, 0, 0);
      }
    }
    unsigned short* alg = al + (size_t)bc * 64 * 64;
    float rsp[4] = {0.f, 0.f, 0.f, 0.f};
#pragma unroll
    for (int mi = 0; mi < 2; mi++)
#pragma unroll
      for (int rr = 0; rr < 4; rr++) {
        int n_l = crow + rr, m_l = (mh * 2 + mi) * 16 + l15;
        float mv = (n_l >= m_l) ? a1[mi][rr] : 0.f;
        alg[n_l * 64 + m_l] = f2bf(mv);
        rsp[rr] += mv;
      }
#pragma unroll
    for (int rr = 0; rr < 4; rr++) {
      float r = rsp[rr];
      r += __shfl_xor(r, 1); r += __shfl_xor(r, 2);
      r += __shfl_xor(r, 4); r += __shfl_xor(r, 8);
      if (l15 == 0) rsum_l[mh][crow + rr] = r;
    }
  }
  {  // kT pack (K''^T, m-fast)
    int d = tid & 127, mh2 = tid >> 7;
#pragma unroll
    for (int mg = 0; mg < 2; mg++) {
      ushort8 pk;
#pragma unroll
      for (int i = 0; i < 8; i++) pk[i] = qkv[1][mh2 * 16 + mg * 8 + i][d];
      *(ushort8*)&kT[d][mh2 * 16 + mg * 8] = pk;
    }
  }
  {  // vT raw pack (V^T, unscaled)
    int d = tid & 127, mh2 = tid >> 7;
#pragma unroll
    for (int mg = 0; mg < 2; mg++) {
      ushort8 pk;
#pragma unroll
      for (int i = 0; i < 8; i++) pk[i] = qkv[2][mh2 * 16 + mg * 8 + i][d];
      *(ushort8*)&vT[d][mh2 * 16 + mg * 8] = pk;
    }
  }
  __syncthreads();   // csp, rsum_l, kT, vT(raw) ready

  // ---- P3: s = rowsum(A) + Q'.csp ; invl ----
  {
    int row = tid >> 3, part = tid & 7;
    ushort8 q8a = *(const ushort8*)&qkv[0][row][part * 16];
    ushort8 q8b = *(const ushort8*)&qkv[0][row][part * 16 + 8];
    float dot = 0.f;
#pragma unroll
    for (int ii = 0; ii < 8; ii++) {
      dot = fmaf(bf2f(q8a[ii]), csp[part * 16 + ii], dot);
      dot = fmaf(bf2f(q8b[ii]), csp[part * 16 + 8 + ii], dot);
    }
    dot += __shfl_xor(dot, 1); dot += __shfl_xor(dot, 2); dot += __shfl_xor(dot, 4);
    if (part == 0) {
      float s = rsum_l[0][row] + rsum_l[1][row] + dot;
      invl[row] = 1.f / fmaxf(fabsf(s), 1.f);
    }
  }
  __syncthreads();   // invl ready

  // ---- P4: scale vT in place by invl[m] ----
  {
    int d = tid >> 2, ms = (tid & 3) * 16;
#pragma unroll
    for (int g = 0; g < 2; g++) {
      ushort8 v8 = *(const ushort8*)&vT[d][ms + g * 8];
      ushort8 o;
#pragma unroll
      for (int ii = 0; ii < 8; ii++) o[ii] = f2bf(bf2f(v8[ii]) * invl[ms + g * 8 + ii]);
      *(ushort8*)&vT[d][ms + g * 8] = o;
    }
  }
  __syncthreads();   // vT = V'^T ready

  // ---- P5: Hc = (K''^T V')^T via MFMA ; vbT global write ----
  {
    f32x4 hacc[8];
#pragma unroll
    for (int j = 0; j < 8; j++) hacc[j] = (f32x4){0.f, 0.f, 0.f, 0.f};
#pragma unroll
    for (int t = 0; t < 2; t++) {
      int k0 = t * 32 + kg;
      short8 a2 = *(const short8*)&vT[w * 16 + l15][k0];
#pragma unroll
      for (int j = 0; j < 8; j++) {
        short8 bf = *(const short8*)&kT[j * 16 + l15][k0];
        hacc[j] = __builtin_amdgcn_mfma_f32_16x16x32_bf16(a2, bf, hacc[j], 0, 0, 0);
      }
    }
    unsigned short* g = Hc + (size_t)bc * D * D;
#pragma unroll
    for (int j = 0; j < 8; j++)
#pragma unroll
      for (int rr = 0; rr < 4; rr++)
        g[(size_t)(w * 16 + (lane >> 4) * 4 + rr) * D + j * 16 + l15] =
            f2bf(hacc[j][rr]);
  }
  {
    int d = tid >> 2, pp = (tid & 3) * 16;
    unsigned short* dst = vbT + (size_t)bc * D * C + (size_t)d * C + pp;
    *(ushort8*)(dst) = *(const ushort8*)&vT[d][pp];
    *(ushort8*)(dst + 8) = *(const ushort8*)&vT[d][pp + 8];
  }
}

// ---------------- K2: HS = exclusive chunk prefix of Hc ----------------
__global__ __launch_bounds__(64) void k_gscan(const unsigned short* __restrict__ Hc,
                                              unsigned short* __restrict__ HS) {
  int b = blockIdx.x, gy = blockIdx.y, t = threadIdx.x;
  int d2 = gy * 4 + (t >> 4), d1 = (t & 15) * 8;
  size_t off = ((size_t)(b * NC) * D + d2) * D + d1;
  ushort8 v[NC];
#pragma unroll
  for (int c = 0; c < NC; c++)
    v[c] = *(const ushort8*)(Hc + off + (size_t)c * D * D);
  float run[8];
#pragma unroll
  for (int j = 0; j < 8; j++) run[j] = 0.f;
#pragma unroll
  for (int c = 0; c < NC; c++) {
    ushort8 o;
#pragma unroll
    for (int j = 0; j < 8; j++) {
      o[j] = f2bf(run[j]);
      run[j] += bf2f(v[c][j]);
    }
    *(ushort8*)(HS + off + (size_t)c * D * D) = o;
  }
}

// ---------------- K3: out = Q'@SE + A@V' (512 threads, no LDS) ------------------
__global__ __launch_bounds__(512) void k_out(
    const unsigned short* __restrict__ qb, const unsigned short* __restrict__ al,
    const unsigned short* __restrict__ vbT, const unsigned short* __restrict__ HS,
    float* __restrict__ out) {
  int bc = blockIdx.x, tid = threadIdx.x, w = tid >> 6, lane = tid & 63;
  int l15 = lane & 15;
  size_t base = (size_t)bc * C * D;
  int kg = (lane >> 4) * 8;
  int rt = w >> 1, ch = w & 1;
  int arow = rt * 16 + l15;
  int crow = rt * 16 + (lane >> 4) * 4;

  f32x4 acc[4];
#pragma unroll
  for (int j = 0; j < 4; j++) acc[j] = (f32x4){0.f, 0.f, 0.f, 0.f};
  const unsigned short* hrow = HS + (size_t)bc * D * D;
#pragma unroll
  for (int t = 0; t < 4; t++) {
    int k0 = t * 32 + kg;
    short8 af = *(const short8*)(qb + base + (size_t)arow * D + k0);
#pragma unroll
    for (int jj = 0; jj < 4; jj++) {
      int j = ch * 4 + jj;
      short8 bf = *(const short8*)(hrow + (size_t)(j * 16 + l15) * D + k0);
      acc[jj] = __builtin_amdgcn_mfma_f32_16x16x32_bf16(af, bf, acc[jj], 0, 0, 0);
    }
  }
  const unsigned short* alg = al + (size_t)bc * 64 * 64;
  const unsigned short* vt = vbT + (size_t)bc * D * C;
#pragma unroll
  for (int t = 0; t < 2; t++) {
    int k0 = t * 32 + kg;
    short8 af = *(const short8*)(alg + (size_t)arow * 64 + k0);
#pragma unroll
    for (int jj = 0; jj < 4; jj++) {
      int j = ch * 4 + jj;
      short8 bf = *(const short8*)(vt + (size_t)(j * 16 + l15) * C + k0);
      acc[jj] = __builtin_amdgcn_mfma_f32_16x16x32_bf16(af, bf, acc[jj], 0, 0, 0);
    }
  }
#pragma unroll
  for (int jj = 0; jj < 4; jj++)
#pragma unroll
    for (int rr = 0; rr < 4; rr++)
      out[base + (size_t)(crow + rr) * D + (ch * 4 + jj) * 16 + l15] = acc[jj][rr];
}

extern "C" void kernel_launch(void* const* d_in, const int* in_sizes, int n_in,
                              void* d_out, int out_size, void* d_ws, size_t ws_size,
                              hipStream_t stream) {
  const float* xq = (const float*)d_in[0];
  const float* xk = (const float*)d_in[1];
  const float* xv = (const float*)d_in[2];
  const float* W  = (const float*)d_in[3];
  float* out = (float*)d_out;

  char* p = (char*)d_ws;
  float* yc = (float*)p;                     p += (size_t)NCH * D * 4;
  unsigned short* qb  = (unsigned short*)p;  p += (size_t)BS * D * 2;
  unsigned short* al  = (unsigned short*)p;  p += (size_t)NCH * C * C * 2;
  unsigned short* vbT = (unsigned short*)p;  p += (size_t)NCH * D * C * 2;
  unsigned short* Hc  = (unsigned short*)p;  p += (size_t)NCH * D * D * 2;
  unsigned short* HS  = (unsigned short*)p;  p += (size_t)NCH * D * D * 2;

  hipLaunchKernelGGL(k_y, dim3(NCH), dim3(128), 0, stream, xk, yc);
  hipLaunchKernelGGL(k_big, dim3(NCH), dim3(512), 0, stream,
                     xq, xk, xv, W, yc, qb, al, vbT, Hc);
  hipLaunchKernelGGL(k_gscan, dim3(B, 32), dim3(64), 0, stream, Hc, HS);
  hipLaunchKernelGGL(k_out, dim3(NCH), dim3(512), 0, stream, qb, al, vbT, HS, out);
}